// Round 17
// baseline (273.416 us; speedup 1.0000x reference)
//
#include <hip/hip_runtime.h>
#include <hip/hip_bf16.h>

#define BB 16
#define NN 10
#define CC 128
#define HWD 2304            // 48*48
#define DD (CC*HWD)         // 294912
#define NC (NN*CC)          // 1280

#define CHP 72              // hw-chunks per (b,n) for dot partials

#define BM 256
#define BN 256
#define BK 32               // ring stage quantum
#define TK (NC/BK)          // 40 K-tiles

typedef __bf16 bf16x8 __attribute__((ext_vector_type(8)));
typedef float  f32x4  __attribute__((ext_vector_type(4)));
typedef float  f32x16 __attribute__((ext_vector_type(16)));

#define XT_BYTES ((size_t)BB*HWD*NC*2)       // 94,371,840
#define W2_BYTES ((size_t)BB*NC*NC*2)        // 52,428,800
#define PART_FLOATS (BB*NN*CHP*3)            // 34,560
#define HEAD ((size_t)262144)                // part + coef region

__device__ __forceinline__ ushort f2bf(float f) {
    __hip_bfloat16 h = __float2bfloat16(f);
    return *reinterpret_cast<ushort*>(&h);
}

__device__ __forceinline__ void gload_lds16(const ushort* g, ushort* l) {
    __builtin_amdgcn_global_load_lds(
        (const __attribute__((address_space(1))) void*)(const void*)g,
        (__attribute__((address_space(3))) void*)(void*)l,
        16, 0, 0);
}

// ---------------- Kernel 1: fused transpose+cast+dots — single pass over x ----------------
__global__ __launch_bounds__(256) void k_trans(const float* __restrict__ x,
                                               ushort* __restrict__ xT,
                                               float* __restrict__ part) {
    __shared__ float tile[32*129];
    __shared__ float red[4][3];
    int hwt = blockIdx.x;         // 0..71
    int b   = blockIdx.y;         // 0..15
    int t = threadIdx.x;
    int hw0 = hwt*32;
    const float* xb = x + (size_t)b*NN*DD;

    int c_[4], ch_[4];
    size_t off_[4];
    #pragma unroll
    for (int i = 0; i < 4; ++i) {
        int s = i*256 + t;
        c_[i] = s >> 3; ch_[i] = s & 7;
        off_[i] = (size_t)c_[i]*HWD + hw0 + ch_[i]*4;
    }

    float4 s0[4], s1[4], s2[4], s3[4];
    #pragma unroll
    for (int i = 0; i < 4; ++i) s0[i] = *(const float4*)(xb + (size_t)0*DD + off_[i]);
    #pragma unroll
    for (int i = 0; i < 4; ++i) s1[i] = *(const float4*)(xb + (size_t)1*DD + off_[i]);
    #pragma unroll
    for (int i = 0; i < 4; ++i) s2[i] = *(const float4*)(xb + (size_t)2*DD + off_[i]);

    int w = t >> 6, l = t & 63;

    for (int n = 0; n < NN; ++n) {
        int n3 = (n + 3) % NN;
        #pragma unroll
        for (int i = 0; i < 4; ++i) s3[i] = *(const float4*)(xb + (size_t)n3*DD + off_[i]);

        float d0 = 0.f, d1 = 0.f, d2 = 0.f;
        #pragma unroll
        for (int i = 0; i < 4; ++i) {
            d0 += s0[i].x*s0[i].x + s0[i].y*s0[i].y + s0[i].z*s0[i].z + s0[i].w*s0[i].w;
            d1 += s0[i].x*s1[i].x + s0[i].y*s1[i].y + s0[i].z*s1[i].z + s0[i].w*s1[i].w;
            d2 += s0[i].x*s2[i].x + s0[i].y*s2[i].y + s0[i].z*s2[i].z + s0[i].w*s2[i].w;
        }
        for (int o = 32; o > 0; o >>= 1) {
            d0 += __shfl_down(d0, o);
            d1 += __shfl_down(d1, o);
            d2 += __shfl_down(d2, o);
        }
        if (l == 0) { red[w][0] = d0; red[w][1] = d1; red[w][2] = d2; }

        #pragma unroll
        for (int i = 0; i < 4; ++i) {
            int hwb = ch_[i]*4, cc = c_[i];
            tile[(hwb+0)*129 + cc] = s0[i].x;
            tile[(hwb+1)*129 + cc] = s0[i].y;
            tile[(hwb+2)*129 + cc] = s0[i].z;
            tile[(hwb+3)*129 + cc] = s0[i].w;
        }
        __syncthreads();

        if (t == 0) {
            float r0 = 0.f, r1 = 0.f, r2 = 0.f;
            #pragma unroll
            for (int i = 0; i < 4; ++i) { r0 += red[i][0]; r1 += red[i][1]; r2 += red[i][2]; }
            float* o = part + ((size_t)(b*NN + n)*CHP + hwt)*3;
            o[0] = r0; o[1] = r1; o[2] = r2;
        }

        int hwl = t >> 4;             // 0..15
        int cc0 = (t & 15) * 8;       // 0..120
        #pragma unroll
        for (int p = 0; p < 2; ++p) {
            int hw = p*16 + hwl;
            const float* src = &tile[hw*129 + cc0];
            union { ushort us[8]; uint4 v; } pk;
            #pragma unroll
            for (int j = 0; j < 8; ++j) pk.us[j] = f2bf(src[j]);
            ushort* dst = xT + (size_t)b*HWD*NC + (size_t)(hw0 + hw)*NC + n*CC + cc0;
            *(uint4*)dst = pk.v;
        }
        __syncthreads();
        #pragma unroll
        for (int i = 0; i < 4; ++i) { s0[i] = s1[i]; s1[i] = s2[i]; s2[i] = s3[i]; }
    }
}

// ---------------- Kernel 2: softmax -> combination coefficients ----------------
__global__ void k_coef(const float* __restrict__ part,
                       const float* __restrict__ pos_dec,
                       const float* __restrict__ len_dec,
                       float* __restrict__ coef) {
    int bn = threadIdx.x;
    if (bn >= BB*NN) return;
    int n = bn % NN;
    float d0 = 0.f, d1 = 0.f, d2 = 0.f;
    const float* p = part + (size_t)bn*CHP*3;
    for (int i = 0; i < CHP; ++i) { d0 += p[i*3]; d1 += p[i*3+1]; d2 += p[i*3+2]; }
    float pd = pos_dec[n], ld = len_dec[n];
    float l0 = (1.f - pd)*d0 + pd*d1;
    float l1 = ld*((1.f - pd)*d1 + pd*d2);
    float m  = fmaxf(l0, l1);
    float e0 = expf(l0 - m), e1 = expf(l1 - m);
    float inv = 1.f/(e0 + e1);
    float a0 = e0*inv, a1 = e1*inv;
    coef[bn*3+0] = a0*(1.f - pd);
    coef[bn*3+1] = a0*pd + a1*ld*(1.f - pd);
    coef[bn*3+2] = a1*ld*pd;
}

// ---------------- Kernel 3a: W2[b][o][mc] = folded per-batch weights (bf16) ----------------
__global__ __launch_bounds__(256) void k_w2(const float* __restrict__ w,
                                            const float* __restrict__ coef,
                                            ushort* __restrict__ w2) {
    int b = blockIdx.y;
    size_t eid = ((size_t)blockIdx.x*256 + threadIdx.x)*8;
    int o  = (int)(eid / NC);
    int mc = (int)(eid % NC);
    int m = mc >> 7, c = mc & 127;
    int m1 = (m + 9) % 10, m2 = (m + 8) % 10;
    float c0 = coef[(b*NN + m )*3 + 0];
    float c1 = coef[(b*NN + m1)*3 + 1];
    float c2 = coef[(b*NN + m2)*3 + 2];
    const float* wr = w + (size_t)o*NC;
    float4 a0 = *(const float4*)(wr + m *128 + c);
    float4 a1 = *(const float4*)(wr + m *128 + c + 4);
    float4 u0 = *(const float4*)(wr + m1*128 + c);
    float4 u1 = *(const float4*)(wr + m1*128 + c + 4);
    float4 v0 = *(const float4*)(wr + m2*128 + c);
    float4 v1 = *(const float4*)(wr + m2*128 + c + 4);
    union { ushort us[8]; uint4 v; } pk;
    pk.us[0] = f2bf(c0*a0.x + c1*u0.x + c2*v0.x);
    pk.us[1] = f2bf(c0*a0.y + c1*u0.y + c2*v0.y);
    pk.us[2] = f2bf(c0*a0.z + c1*u0.z + c2*v0.z);
    pk.us[3] = f2bf(c0*a0.w + c1*u0.w + c2*v0.w);
    pk.us[4] = f2bf(c0*a1.x + c1*u1.x + c2*v1.x);
    pk.us[5] = f2bf(c0*a1.y + c1*u1.y + c2*v1.y);
    pk.us[6] = f2bf(c0*a1.z + c1*u1.z + c2*v1.z);
    pk.us[7] = f2bf(c0*a1.w + c1*u1.w + c2*v1.w);
    *(uint4*)(w2 + (size_t)b*NC*NC + eid) = pk.v;
}

// ---------------- Kernel 3b (fallback): conv_w fp32 -> bf16 ----------------
__global__ __launch_bounds__(256) void k_wconv(const float* __restrict__ w,
                                               ushort* __restrict__ wb) {
    int i = blockIdx.x*blockDim.x + threadIdx.x;
    size_t idx = (size_t)i*4;
    if (idx >= (size_t)NC*NC) return;
    float4 a = *(const float4*)(w + idx);
    ushort4 o;
    o.x = f2bf(a.x); o.y = f2bf(a.y); o.z = f2bf(a.z); o.w = f2bf(a.w);
    *(ushort4*)(wb + idx) = o;
}

// ---------------- Kernel 4 (fallback): featT combo (coef-dependent) ----------------
__global__ __launch_bounds__(256) void k_feat(const float* __restrict__ x,
                                              const float* __restrict__ coef,
                                              ushort* __restrict__ featT) {
    __shared__ float tile[32*129];
    int hwt = blockIdx.x;
    int b   = blockIdx.y;
    int t = threadIdx.x;
    int hw0 = hwt*32;
    const float* xb = x + (size_t)b*NN*DD;

    int c_[4], ch_[4];
    size_t off_[4];
    #pragma unroll
    for (int i = 0; i < 4; ++i) {
        int s = i*256 + t;
        c_[i] = s >> 3; ch_[i] = s & 7;
        off_[i] = (size_t)c_[i]*HWD + hw0 + ch_[i]*4;
    }

    float4 s0[4], s1[4], s2[4], s3[4];
    #pragma unroll
    for (int i = 0; i < 4; ++i) s0[i] = *(const float4*)(xb + (size_t)0*DD + off_[i]);
    #pragma unroll
    for (int i = 0; i < 4; ++i) s1[i] = *(const float4*)(xb + (size_t)1*DD + off_[i]);
    #pragma unroll
    for (int i = 0; i < 4; ++i) s2[i] = *(const float4*)(xb + (size_t)2*DD + off_[i]);

    for (int n = 0; n < NN; ++n) {
        int n3 = (n + 3) % NN;
        #pragma unroll
        for (int i = 0; i < 4; ++i) s3[i] = *(const float4*)(xb + (size_t)n3*DD + off_[i]);

        int bn = b*NN + n;
        float c0 = coef[bn*3+0], c1 = coef[bn*3+1], c2 = coef[bn*3+2];

        #pragma unroll
        for (int i = 0; i < 4; ++i) {
            int hwb = ch_[i]*4, cc = c_[i];
            tile[(hwb+0)*129 + cc] = c0*s0[i].x + c1*s1[i].x + c2*s2[i].x;
            tile[(hwb+1)*129 + cc] = c0*s0[i].y + c1*s1[i].y + c2*s2[i].y;
            tile[(hwb+2)*129 + cc] = c0*s0[i].z + c1*s1[i].z + c2*s2[i].z;
            tile[(hwb+3)*129 + cc] = c0*s0[i].w + c1*s1[i].w + c2*s2[i].w;
        }
        __syncthreads();

        int hwl = t >> 4;
        int cc0 = (t & 15) * 8;
        #pragma unroll
        for (int p = 0; p < 2; ++p) {
            int hw = p*16 + hwl;
            const float* src = &tile[hw*129 + cc0];
            union { ushort us[8]; uint4 v; } pk;
            #pragma unroll
            for (int j = 0; j < 8; ++j) pk.us[j] = f2bf(src[j]);
            ushort* dst = featT + (size_t)b*HWD*NC + (size_t)(hw0 + hw)*NC + n*CC + cc0;
            *(uint4*)dst = pk.v;
        }
        __syncthreads();
        #pragma unroll
        for (int i = 0; i < 4; ++i) { s0[i] = s1[i]; s1[i] = s2[i]; s2[i] = s3[i]; }
    }
}

// ---------------- Kernel 5: 256x256, BK=32 4-slot ring (3 tiles in flight), minimal barriers ----
// R16 structure with pipeline depth 1 -> 3 stage quanta. Per iter:
//   STAGE(slot kt+3) ; COMP(slot kt) [compiler-interleaved] ; vmcnt(8) ; barrier
// Ledger: outstanding = 12 loads (tiles kt+1..kt+3); vmcnt(8) retires tile kt+1.
// Slot WAR covered by previous iteration's barrier. No lgkmcnt pins (R16 lesson).
// 32x32x16 MFMA; swizzle phys_chunk = c ^ ((row>>1)&3); conflicts are benign 2-way.
#define BAR()   __builtin_amdgcn_s_barrier()
#define SB()    __builtin_amdgcn_sched_barrier(0)
#define VM(N)   asm volatile("s_waitcnt vmcnt(" #N ")" ::: "memory")

__global__ __launch_bounds__(512, 2) void k_gemm(const ushort* __restrict__ Amat,
                                                 const ushort* __restrict__ Bmat,
                                                 const float* __restrict__ bias,
                                                 const float* __restrict__ x,
                                                 float* __restrict__ out,
                                                 size_t aStride) {
    __shared__ ushort L[4][2][BM*BK];   // 4 slots x (A,B) x 16 KiB = 128 KiB

    int bid = blockIdx.x;
    int wkid = (bid & 7) * 90 + (bid >> 3);   // bijective XCD swizzle (720 = 8*90)
    int b   = wkid / 45;
    int r45 = wkid % 45;
    int hwt = r45 / 5;
    int ot  = r45 % 5;
    int o0 = ot*BM, hw0 = hwt*BN;

    int t = threadIdx.x;
    int l = t & 63;
    int w = t >> 6;
    int wr = w >> 2, wc = w & 3;      // 2(M) x 4(N) waves; wave tile 128x64

    const ushort* Ag = Amat + (size_t)b*aStride + (size_t)o0*NC;
    const ushort* Bg = Bmat + (size_t)b*HWD*NC + (size_t)hw0*NC;

    int r0 = t >> 2, c0 = t & 3;
    size_t g0 = (size_t)r0*NC + (size_t)((c0 ^ ((r0 >> 1) & 3)) * 8);
    size_t g1 = g0 + (size_t)128*NC;

#define STAGE(sl_, kt_) do { \
    size_t ko_ = (size_t)(kt_)*BK; \
    gload_lds16(Ag + g0 + ko_, &L[sl_][0][t*8]); \
    gload_lds16(Ag + g1 + ko_, &L[sl_][0][(512 + t)*8]); \
    gload_lds16(Bg + g0 + ko_, &L[sl_][1][t*8]); \
    gload_lds16(Bg + g1 + ko_, &L[sl_][1][(512 + t)*8]); } while (0)

    // 32x32x16 fragment constants (R13/R16 layout)
    int fr32 = l & 31;
    int kh   = l >> 5;                       // 0/1
    int sw   = (fr32 >> 1) & 3;
    int kcA  = ((kh)     ^ sw) << 3;         // chunk for kq=0
    int kcB  = ((2 | kh) ^ sw) << 3;         // chunk for kq=1
    int rA   = (wr*128 + fr32)*32;           // + mt*1024
    int rB   = (wc*64  + fr32)*32;           // + nt*1024

    f32x16 acc[4][2] = {};

    // compute one BK=32 tile (16 MFMA, 12 ds_read_b128) — compiler schedules
#define COMP(sl_) do { \
    const ushort* Ar_ = &L[sl_][0][0]; \
    const ushort* Br_ = &L[sl_][1][0]; \
    bf16x8 a_[8], b0_, b1_, b2_, b3_; \
    _Pragma("unroll") \
    for (int mt = 0; mt < 4; ++mt) { \
        a_[mt*2+0] = *(const bf16x8*)&Ar_[rA + mt*1024 + kcA]; \
        a_[mt*2+1] = *(const bf16x8*)&Ar_[rA + mt*1024 + kcB]; \
    } \
    b0_ = *(const bf16x8*)&Br_[rB + kcA]; \
    b1_ = *(const bf16x8*)&Br_[rB + kcB]; \
    b2_ = *(const bf16x8*)&Br_[rB + 1024 + kcA]; \
    b3_ = *(const bf16x8*)&Br_[rB + 1024 + kcB]; \
    _Pragma("unroll") \
    for (int mt = 0; mt < 4; ++mt) { \
        acc[mt][0] = __builtin_amdgcn_mfma_f32_32x32x16_bf16(a_[mt*2+0], b0_, acc[mt][0], 0, 0, 0); \
        acc[mt][0] = __builtin_amdgcn_mfma_f32_32x32x16_bf16(a_[mt*2+1], b1_, acc[mt][0], 0, 0, 0); \
        acc[mt][1] = __builtin_amdgcn_mfma_f32_32x32x16_bf16(a_[mt*2+0], b2_, acc[mt][1], 0, 0, 0); \
        acc[mt][1] = __builtin_amdgcn_mfma_f32_32x32x16_bf16(a_[mt*2+1], b3_, acc[mt][1], 0, 0, 0); \
    } } while (0)

    // prologue: stage tiles 0,1,2 into slots 0,1,2 (12 loads); wait tile 0
    STAGE(0, 0);
    STAGE(1, 1);
    STAGE(2, 2);
    VM(8);
    BAR();

    for (int kt = 0; kt < TK - 3; ++kt) {
        STAGE((kt + 3) & 3, kt + 3);   // issue 3 tiles ahead
        SB();                          // keep stage issue above compute
        COMP(kt & 3);
        VM(8);                         // tile kt+1 complete; kt+2, kt+3 in flight
        BAR();
    }
    // kt = TK-3: no stage
    COMP((TK - 3) & 3);
    VM(4);                             // tile TK-2 complete; TK-1 in flight
    BAR();
    // kt = TK-2
    COMP((TK - 2) & 3);
    VM(0);                             // drain tile TK-1
    BAR();
    // kt = TK-1
    COMP((TK - 1) & 3);

#undef COMP
#undef STAGE

    // epilogue: + bias + residual x  (32x32 C/D mapping)
    #pragma unroll
    for (int mt = 0; mt < 4; ++mt) {
        #pragma unroll
        for (int nt = 0; nt < 2; ++nt) {
            int col = hw0 + wc*64 + nt*32 + fr32;
            #pragma unroll
            for (int reg = 0; reg < 16; ++reg) {
                int ro = o0 + wr*128 + mt*32 + (reg & 3) + 8*(reg >> 2) + 4*kh;
                size_t idx = (size_t)b*NC*HWD + (size_t)ro*HWD + col;
                out[idx] = acc[mt][nt][reg] + bias[ro] + x[idx];
            }
        }
    }
}

extern "C" void kernel_launch(void* const* d_in, const int* in_sizes, int n_in,
                              void* d_out, int out_size, void* d_ws, size_t ws_size,
                              hipStream_t stream) {
    const float* x       = (const float*)d_in[0];
    const float* pos_dec = (const float*)d_in[1];
    const float* len_dec = (const float*)d_in[2];
    const float* conv_w  = (const float*)d_in[3];
    const float* conv_b  = (const float*)d_in[4];
    float* out = (float*)d_out;

    char* ws = (char*)d_ws;
    float*  part = (float*)ws;                    // 138,240 B
    float*  coef = part + PART_FLOATS;            // 1,920 B
    ushort* xT   = (ushort*)(ws + HEAD);          // 94,371,840 B (xT or featT)

    k_trans<<<dim3(CHP, BB), 256, 0, stream>>>(x, xT, part);
    k_coef <<<dim3(1), 256, 0, stream>>>(part, pos_dec, len_dec, coef);

    if (ws_size >= HEAD + XT_BYTES + W2_BYTES) {
        ushort* w2 = (ushort*)(ws + HEAD + XT_BYTES);   // 52,428,800 B
        k_w2  <<<dim3(800, BB), 256, 0, stream>>>(conv_w, coef, w2);
        k_gemm<<<dim3(720), 512, 0, stream>>>(w2, xT, conv_b, x, out, (size_t)NC*NC);
    } else {
        ushort* wb = (ushort*)(ws + HEAD + XT_BYTES);   // 3,276,800 B
        k_wconv<<<dim3(1600), 256, 0, stream>>>(conv_w, wb);
        k_feat <<<dim3(CHP, BB), 256, 0, stream>>>(x, coef, xT);
        k_gemm <<<dim3(720), 512, 0, stream>>>(wb, xT, conv_b, x, out, (size_t)0);
    }
}

// Round 18
// 268.026 us; speedup vs baseline: 1.0201x; 1.0201x over previous
//
#include <hip/hip_runtime.h>
#include <hip/hip_bf16.h>

#define BB 16
#define NN 10
#define CC 128
#define HWD 2304            // 48*48
#define DD (CC*HWD)         // 294912
#define NC (NN*CC)          // 1280

#define CHP 72              // hw-chunks per (b,n) for dot partials

#define BM 256
#define BN 256
#define BK 64
#define TK (NC/BK)          // 20 K-tiles

typedef __bf16 bf16x8 __attribute__((ext_vector_type(8)));
typedef float  f32x4  __attribute__((ext_vector_type(4)));
typedef float  f32x16 __attribute__((ext_vector_type(16)));

#define XT_BYTES ((size_t)BB*HWD*NC*2)       // 94,371,840
#define W2_BYTES ((size_t)BB*NC*NC*2)        // 52,428,800
#define PART_FLOATS (BB*NN*CHP*3)            // 34,560
#define HEAD ((size_t)262144)                // part + coef region

__device__ __forceinline__ ushort f2bf(float f) {
    __hip_bfloat16 h = __float2bfloat16(f);
    return *reinterpret_cast<ushort*>(&h);
}

__device__ __forceinline__ void gload_lds16(const ushort* g, ushort* l) {
    __builtin_amdgcn_global_load_lds(
        (const __attribute__((address_space(1))) void*)(const void*)g,
        (__attribute__((address_space(3))) void*)(void*)l,
        16, 0, 0);
}

// ---------------- Kernel 1: fused transpose+cast+dots — single pass over x ----------------
__global__ __launch_bounds__(256) void k_trans(const float* __restrict__ x,
                                               ushort* __restrict__ xT,
                                               float* __restrict__ part) {
    __shared__ float tile[32*129];
    __shared__ float red[4][3];
    int hwt = blockIdx.x;         // 0..71
    int b   = blockIdx.y;         // 0..15
    int t = threadIdx.x;
    int hw0 = hwt*32;
    const float* xb = x + (size_t)b*NN*DD;

    int c_[4], ch_[4];
    size_t off_[4];
    #pragma unroll
    for (int i = 0; i < 4; ++i) {
        int s = i*256 + t;
        c_[i] = s >> 3; ch_[i] = s & 7;
        off_[i] = (size_t)c_[i]*HWD + hw0 + ch_[i]*4;
    }

    float4 s0[4], s1[4], s2[4], s3[4];
    #pragma unroll
    for (int i = 0; i < 4; ++i) s0[i] = *(const float4*)(xb + (size_t)0*DD + off_[i]);
    #pragma unroll
    for (int i = 0; i < 4; ++i) s1[i] = *(const float4*)(xb + (size_t)1*DD + off_[i]);
    #pragma unroll
    for (int i = 0; i < 4; ++i) s2[i] = *(const float4*)(xb + (size_t)2*DD + off_[i]);

    int w = t >> 6, l = t & 63;

    for (int n = 0; n < NN; ++n) {
        int n3 = (n + 3) % NN;
        #pragma unroll
        for (int i = 0; i < 4; ++i) s3[i] = *(const float4*)(xb + (size_t)n3*DD + off_[i]);

        float d0 = 0.f, d1 = 0.f, d2 = 0.f;
        #pragma unroll
        for (int i = 0; i < 4; ++i) {
            d0 += s0[i].x*s0[i].x + s0[i].y*s0[i].y + s0[i].z*s0[i].z + s0[i].w*s0[i].w;
            d1 += s0[i].x*s1[i].x + s0[i].y*s1[i].y + s0[i].z*s1[i].z + s0[i].w*s1[i].w;
            d2 += s0[i].x*s2[i].x + s0[i].y*s2[i].y + s0[i].z*s2[i].z + s0[i].w*s2[i].w;
        }
        for (int o = 32; o > 0; o >>= 1) {
            d0 += __shfl_down(d0, o);
            d1 += __shfl_down(d1, o);
            d2 += __shfl_down(d2, o);
        }
        if (l == 0) { red[w][0] = d0; red[w][1] = d1; red[w][2] = d2; }

        #pragma unroll
        for (int i = 0; i < 4; ++i) {
            int hwb = ch_[i]*4, cc = c_[i];
            tile[(hwb+0)*129 + cc] = s0[i].x;
            tile[(hwb+1)*129 + cc] = s0[i].y;
            tile[(hwb+2)*129 + cc] = s0[i].z;
            tile[(hwb+3)*129 + cc] = s0[i].w;
        }
        __syncthreads();

        if (t == 0) {
            float r0 = 0.f, r1 = 0.f, r2 = 0.f;
            #pragma unroll
            for (int i = 0; i < 4; ++i) { r0 += red[i][0]; r1 += red[i][1]; r2 += red[i][2]; }
            float* o = part + ((size_t)(b*NN + n)*CHP + hwt)*3;
            o[0] = r0; o[1] = r1; o[2] = r2;
        }

        int hwl = t >> 4;             // 0..15
        int cc0 = (t & 15) * 8;       // 0..120
        #pragma unroll
        for (int p = 0; p < 2; ++p) {
            int hw = p*16 + hwl;
            const float* src = &tile[hw*129 + cc0];
            union { ushort us[8]; uint4 v; } pk;
            #pragma unroll
            for (int j = 0; j < 8; ++j) pk.us[j] = f2bf(src[j]);
            ushort* dst = xT + (size_t)b*HWD*NC + (size_t)(hw0 + hw)*NC + n*CC + cc0;
            *(uint4*)dst = pk.v;
        }
        __syncthreads();
        #pragma unroll
        for (int i = 0; i < 4; ++i) { s0[i] = s1[i]; s1[i] = s2[i]; s2[i] = s3[i]; }
    }
}

// ---------------- Kernel 2: softmax -> combination coefficients ----------------
__global__ void k_coef(const float* __restrict__ part,
                       const float* __restrict__ pos_dec,
                       const float* __restrict__ len_dec,
                       float* __restrict__ coef) {
    int bn = threadIdx.x;
    if (bn >= BB*NN) return;
    int n = bn % NN;
    float d0 = 0.f, d1 = 0.f, d2 = 0.f;
    const float* p = part + (size_t)bn*CHP*3;
    for (int i = 0; i < CHP; ++i) { d0 += p[i*3]; d1 += p[i*3+1]; d2 += p[i*3+2]; }
    float pd = pos_dec[n], ld = len_dec[n];
    float l0 = (1.f - pd)*d0 + pd*d1;
    float l1 = ld*((1.f - pd)*d1 + pd*d2);
    float m  = fmaxf(l0, l1);
    float e0 = expf(l0 - m), e1 = expf(l1 - m);
    float inv = 1.f/(e0 + e1);
    float a0 = e0*inv, a1 = e1*inv;
    coef[bn*3+0] = a0*(1.f - pd);
    coef[bn*3+1] = a0*pd + a1*ld*(1.f - pd);
    coef[bn*3+2] = a1*ld*pd;
}

// ---------------- Kernel 3a: W2[b][o][mc] = folded per-batch weights (bf16) ----------------
__global__ __launch_bounds__(256) void k_w2(const float* __restrict__ w,
                                            const float* __restrict__ coef,
                                            ushort* __restrict__ w2) {
    int b = blockIdx.y;
    size_t eid = ((size_t)blockIdx.x*256 + threadIdx.x)*8;
    int o  = (int)(eid / NC);
    int mc = (int)(eid % NC);
    int m = mc >> 7, c = mc & 127;
    int m1 = (m + 9) % 10, m2 = (m + 8) % 10;
    float c0 = coef[(b*NN + m )*3 + 0];
    float c1 = coef[(b*NN + m1)*3 + 1];
    float c2 = coef[(b*NN + m2)*3 + 2];
    const float* wr = w + (size_t)o*NC;
    float4 a0 = *(const float4*)(wr + m *128 + c);
    float4 a1 = *(const float4*)(wr + m *128 + c + 4);
    float4 u0 = *(const float4*)(wr + m1*128 + c);
    float4 u1 = *(const float4*)(wr + m1*128 + c + 4);
    float4 v0 = *(const float4*)(wr + m2*128 + c);
    float4 v1 = *(const float4*)(wr + m2*128 + c + 4);
    union { ushort us[8]; uint4 v; } pk;
    pk.us[0] = f2bf(c0*a0.x + c1*u0.x + c2*v0.x);
    pk.us[1] = f2bf(c0*a0.y + c1*u0.y + c2*v0.y);
    pk.us[2] = f2bf(c0*a0.z + c1*u0.z + c2*v0.z);
    pk.us[3] = f2bf(c0*a0.w + c1*u0.w + c2*v0.w);
    pk.us[4] = f2bf(c0*a1.x + c1*u1.x + c2*v1.x);
    pk.us[5] = f2bf(c0*a1.y + c1*u1.y + c2*v1.y);
    pk.us[6] = f2bf(c0*a1.z + c1*u1.z + c2*v1.z);
    pk.us[7] = f2bf(c0*a1.w + c1*u1.w + c2*v1.w);
    *(uint4*)(w2 + (size_t)b*NC*NC + eid) = pk.v;
}

// ---------------- Kernel 3b (fallback): conv_w fp32 -> bf16 ----------------
__global__ __launch_bounds__(256) void k_wconv(const float* __restrict__ w,
                                               ushort* __restrict__ wb) {
    int i = blockIdx.x*blockDim.x + threadIdx.x;
    size_t idx = (size_t)i*4;
    if (idx >= (size_t)NC*NC) return;
    float4 a = *(const float4*)(w + idx);
    ushort4 o;
    o.x = f2bf(a.x); o.y = f2bf(a.y); o.z = f2bf(a.z); o.w = f2bf(a.w);
    *(ushort4*)(wb + idx) = o;
}

// ---------------- Kernel 4 (fallback): featT combo (coef-dependent) ----------------
__global__ __launch_bounds__(256) void k_feat(const float* __restrict__ x,
                                              const float* __restrict__ coef,
                                              ushort* __restrict__ featT) {
    __shared__ float tile[32*129];
    int hwt = blockIdx.x;
    int b   = blockIdx.y;
    int t = threadIdx.x;
    int hw0 = hwt*32;
    const float* xb = x + (size_t)b*NN*DD;

    int c_[4], ch_[4];
    size_t off_[4];
    #pragma unroll
    for (int i = 0; i < 4; ++i) {
        int s = i*256 + t;
        c_[i] = s >> 3; ch_[i] = s & 7;
        off_[i] = (size_t)c_[i]*HWD + hw0 + ch_[i]*4;
    }

    float4 s0[4], s1[4], s2[4], s3[4];
    #pragma unroll
    for (int i = 0; i < 4; ++i) s0[i] = *(const float4*)(xb + (size_t)0*DD + off_[i]);
    #pragma unroll
    for (int i = 0; i < 4; ++i) s1[i] = *(const float4*)(xb + (size_t)1*DD + off_[i]);
    #pragma unroll
    for (int i = 0; i < 4; ++i) s2[i] = *(const float4*)(xb + (size_t)2*DD + off_[i]);

    for (int n = 0; n < NN; ++n) {
        int n3 = (n + 3) % NN;
        #pragma unroll
        for (int i = 0; i < 4; ++i) s3[i] = *(const float4*)(xb + (size_t)n3*DD + off_[i]);

        int bn = b*NN + n;
        float c0 = coef[bn*3+0], c1 = coef[bn*3+1], c2 = coef[bn*3+2];

        #pragma unroll
        for (int i = 0; i < 4; ++i) {
            int hwb = ch_[i]*4, cc = c_[i];
            tile[(hwb+0)*129 + cc] = c0*s0[i].x + c1*s1[i].x + c2*s2[i].x;
            tile[(hwb+1)*129 + cc] = c0*s0[i].y + c1*s1[i].y + c2*s2[i].y;
            tile[(hwb+2)*129 + cc] = c0*s0[i].z + c1*s1[i].z + c2*s2[i].z;
            tile[(hwb+3)*129 + cc] = c0*s0[i].w + c1*s1[i].w + c2*s2[i].w;
        }
        __syncthreads();

        int hwl = t >> 4;
        int cc0 = (t & 15) * 8;
        #pragma unroll
        for (int p = 0; p < 2; ++p) {
            int hw = p*16 + hwl;
            const float* src = &tile[hw*129 + cc0];
            union { ushort us[8]; uint4 v; } pk;
            #pragma unroll
            for (int j = 0; j < 8; ++j) pk.us[j] = f2bf(src[j]);
            ushort* dst = featT + (size_t)b*HWD*NC + (size_t)(hw0 + hw)*NC + n*CC + cc0;
            *(uint4*)dst = pk.v;
        }
        __syncthreads();
        #pragma unroll
        for (int i = 0; i < 4; ++i) { s0[i] = s1[i]; s1[i] = s2[i]; s2[i] = s3[i]; }
    }
}

// ---------------- Kernel 5: 256x256x64, 32x32x16 MFMA, MINIMAL barriers (best measured) ----------
// Per K-tile: {stage klo(kt+1); compute klo(kt) [compiler-interleaved ds_read+MFMA];
//              vmcnt(4); barrier;  stage khi(kt+1); compute khi(kt); vmcnt(4); barrier}
// No lgkmcnt(0) pins, no sched_barrier between reads and MFMA. Ledger: at each wait
// the queue holds 8 loads; vmcnt(4) drains the 4 oldest = the half-tile needed
// after the barrier. WAR on buffer reuse covered by the tile-end barrier.
#define BAR()   __builtin_amdgcn_s_barrier()
#define SB()    __builtin_amdgcn_sched_barrier(0)
#define VM(N)   asm volatile("s_waitcnt vmcnt(" #N ")" ::: "memory")

__global__ __launch_bounds__(512, 2) void k_gemm(const ushort* __restrict__ Amat,
                                                 const ushort* __restrict__ Bmat,
                                                 const float* __restrict__ bias,
                                                 const float* __restrict__ x,
                                                 float* __restrict__ out,
                                                 size_t aStride) {
    __shared__ ushort L[2][4][BM*32];   // 2 bufs x 4 regions (Aklo,Akhi,Bklo,Bkhi) x 16 KiB

    int bid = blockIdx.x;
    int wkid = (bid & 7) * 90 + (bid >> 3);   // bijective XCD swizzle (720 = 8*90)
    int b   = wkid / 45;
    int r45 = wkid % 45;
    int hwt = r45 / 5;
    int ot  = r45 % 5;
    int o0 = ot*BM, hw0 = hwt*BN;

    int t = threadIdx.x;
    int l = t & 63;
    int w = t >> 6;
    int wr = w >> 2, wc = w & 3;      // 2(M) x 4(N) waves; wave tile 128x64

    const ushort* Ag = Amat + (size_t)b*aStride + (size_t)o0*NC;
    const ushort* Bg = Bmat + (size_t)b*HWD*NC + (size_t)hw0*NC;

    int r0 = t >> 2, c0 = t & 3;
    size_t g0 = (size_t)r0*NC + (size_t)((c0 ^ ((r0 >> 1) & 3)) * 8);
    size_t g1 = g0 + (size_t)128*NC;

#define STAGE(nb_, reg_, gp_) do { \
    gload_lds16((gp_) + g0, &L[nb_][reg_][t*8]); \
    gload_lds16((gp_) + g1, &L[nb_][reg_][(512 + t)*8]); } while (0)

    // 32x32x16 fragment constants
    int fr32 = l & 31;
    int kh   = l >> 5;                       // 0/1
    int sw   = (fr32 >> 1) & 3;
    int kcA  = ((kh)     ^ sw) << 3;         // chunk for kq=0
    int kcB  = ((2 | kh) ^ sw) << 3;         // chunk for kq=1
    int rA   = (wr*128 + fr32)*32;           // + mt*1024
    int rB   = (wc*64  + fr32)*32;           // + nt*1024

    f32x16 acc[4][2] = {};

    // compute one K-half region (16 MFMA, 12 ds_read_b128) — compiler schedules
#define COMP(Ar_, Br_) do { \
    bf16x8 a_[8], b0_, b1_, b2_, b3_; \
    _Pragma("unroll") \
    for (int mt = 0; mt < 4; ++mt) { \
        a_[mt*2+0] = *(const bf16x8*)&(Ar_)[rA + mt*1024 + kcA]; \
        a_[mt*2+1] = *(const bf16x8*)&(Ar_)[rA + mt*1024 + kcB]; \
    } \
    b0_ = *(const bf16x8*)&(Br_)[rB + kcA]; \
    b1_ = *(const bf16x8*)&(Br_)[rB + kcB]; \
    b2_ = *(const bf16x8*)&(Br_)[rB + 1024 + kcA]; \
    b3_ = *(const bf16x8*)&(Br_)[rB + 1024 + kcB]; \
    _Pragma("unroll") \
    for (int mt = 0; mt < 4; ++mt) { \
        acc[mt][0] = __builtin_amdgcn_mfma_f32_32x32x16_bf16(a_[mt*2+0], b0_, acc[mt][0], 0, 0, 0); \
        acc[mt][0] = __builtin_amdgcn_mfma_f32_32x32x16_bf16(a_[mt*2+1], b1_, acc[mt][0], 0, 0, 0); \
        acc[mt][1] = __builtin_amdgcn_mfma_f32_32x32x16_bf16(a_[mt*2+0], b2_, acc[mt][1], 0, 0, 0); \
        acc[mt][1] = __builtin_amdgcn_mfma_f32_32x32x16_bf16(a_[mt*2+1], b3_, acc[mt][1], 0, 0, 0); \
    } } while (0)

    // prologue: stage tile 0 (klo then khi); wait klo
    STAGE(0, 0, Ag);                 // Aklo(0)
    STAGE(0, 2, Bg);                 // Bklo(0)
    STAGE(0, 1, Ag + 32);            // Akhi(0)
    STAGE(0, 3, Bg + 32);            // Bkhi(0)
    VM(4);
    BAR();

    for (int kt = 0; kt < TK - 1; ++kt) {
        int buf = kt & 1, nbuf = buf ^ 1;
        const ushort* A0 = &L[buf][0][0];
        const ushort* A1 = &L[buf][1][0];
        const ushort* B0 = &L[buf][2][0];
        const ushort* B1 = &L[buf][3][0];
        const ushort* Agk = Ag + (size_t)(kt + 1)*BK;
        const ushort* Bgk = Bg + (size_t)(kt + 1)*BK;

        // ---- half 1: stage klo(kt+1), compute klo(kt) ----
        STAGE(nbuf, 0, Agk);
        STAGE(nbuf, 2, Bgk);
        SB();                          // keep stage issue above compute
        COMP(A0, B0);
        VM(4);                         // khi(kt) ready; klo(kt+1) in flight
        BAR();

        // ---- half 2: stage khi(kt+1), compute khi(kt) ----
        STAGE(nbuf, 1, Agk + 32);
        STAGE(nbuf, 3, Bgk + 32);
        SB();
        COMP(A1, B1);
        VM(4);                         // klo(kt+1) ready; khi(kt+1) in flight
        BAR();
    }

    // ---- last tile (kt = TK-1), peeled: no stages ----
    {
        const int buf = (TK - 1) & 1;
        COMP((&L[buf][0][0]), (&L[buf][2][0]));   // klo
        VM(0);                                     // drain khi(TK-1)
        BAR();
        COMP((&L[buf][1][0]), (&L[buf][3][0]));   // khi
    }
#undef COMP
#undef STAGE

    // epilogue: + bias + residual x  (32x32 C/D mapping)
    #pragma unroll
    for (int mt = 0; mt < 4; ++mt) {
        #pragma unroll
        for (int nt = 0; nt < 2; ++nt) {
            int col = hw0 + wc*64 + nt*32 + fr32;
            #pragma unroll
            for (int reg = 0; reg < 16; ++reg) {
                int ro = o0 + wr*128 + mt*32 + (reg & 3) + 8*(reg >> 2) + 4*kh;
                size_t idx = (size_t)b*NC*HWD + (size_t)ro*HWD + col;
                out[idx] = acc[mt][nt][reg] + bias[ro] + x[idx];
            }
        }
    }
}

extern "C" void kernel_launch(void* const* d_in, const int* in_sizes, int n_in,
                              void* d_out, int out_size, void* d_ws, size_t ws_size,
                              hipStream_t stream) {
    const float* x       = (const float*)d_in[0];
    const float* pos_dec = (const float*)d_in[1];
    const float* len_dec = (const float*)d_in[2];
    const float* conv_w  = (const float*)d_in[3];
    const float* conv_b  = (const float*)d_in[4];
    float* out = (float*)d_out;

    char* ws = (char*)d_ws;
    float*  part = (float*)ws;                    // 138,240 B
    float*  coef = part + PART_FLOATS;            // 1,920 B
    ushort* xT   = (ushort*)(ws + HEAD);          // 94,371,840 B (xT or featT)

    k_trans<<<dim3(CHP, BB), 256, 0, stream>>>(x, xT, part);
    k_coef <<<dim3(1), 256, 0, stream>>>(part, pos_dec, len_dec, coef);

    if (ws_size >= HEAD + XT_BYTES + W2_BYTES) {
        ushort* w2 = (ushort*)(ws + HEAD + XT_BYTES);   // 52,428,800 B
        k_w2  <<<dim3(800, BB), 256, 0, stream>>>(conv_w, coef, w2);
        k_gemm<<<dim3(720), 512, 0, stream>>>(w2, xT, conv_b, x, out, (size_t)NC*NC);
    } else {
        ushort* wb = (ushort*)(ws + HEAD + XT_BYTES);   // 3,276,800 B
        k_wconv<<<dim3(1600), 256, 0, stream>>>(conv_w, wb);
        k_feat <<<dim3(CHP, BB), 256, 0, stream>>>(x, coef, xT);
        k_gemm <<<dim3(720), 512, 0, stream>>>(wb, xT, conv_b, x, out, (size_t)0);
    }
}